// Round 9
// baseline (213.846 us; speedup 1.0000x reference)
//
#include <hip/hip_runtime.h>
#include <hip/hip_bf16.h>
#include <cstddef>
#include <cstdint>

#define NTOK 8192      // N
#define CD   256       // C
#define HWPIX 16384    // H*W = 128*128
#define WIDTH 128
#define NSEQ 1024      // Ns

typedef __attribute__((ext_vector_type(8))) short bfrag;   // 8 bf16 = 4 VGPRs
typedef __attribute__((ext_vector_type(4))) float f32x4;
typedef __attribute__((ext_vector_type(4))) unsigned int u32x4;

__device__ inline unsigned short f2bfu(float f) {
    __hip_bfloat16 h = __float2bfloat16(f);   // RTNE
    unsigned short u;
    __builtin_memcpy(&u, &h, 2);
    return u;
}
__device__ inline unsigned int rtn16(float f) {
    unsigned int u = __builtin_bit_cast(unsigned int, f);
    return u + 0x7fffu + ((u >> 16) & 1u);
}
__device__ inline float bits2f(unsigned int u) {
    return __builtin_bit_cast(float, u);
}
// async global -> LDS, 16 B per lane; lds base wave-uniform, HW adds lane*16
__device__ inline void gld16(const unsigned short* g, const unsigned short* l) {
    __builtin_amdgcn_global_load_lds(
        (const __attribute__((address_space(1))) unsigned int*)g,
        (__attribute__((address_space(3))) unsigned int*)l, 16, 0, 0);
}
// HW bf16 pack, RTNE: low16 = bf16(lo), high16 = bf16(hi). 1 instr.
__device__ inline unsigned int cvtpk(float lo, float hi) {
    unsigned int r;
    asm("v_cvt_pk_bf16_f32 %0, %1, %2" : "=v"(r) : "v"(lo), "v"(hi));
    return r;
}
// key (0..63 within tile) -> K storage slot. Bit permutation
// slot = [b5 b2 | b4 b3 | b1 b0] of key; chosen so that the swapped-QK
// MFMA D-layout (row = quad*4+reg, sub = s) leaves each lane holding
// exactly the keys of its own PV A-operand fragment (lane-local pack).
__device__ inline int kslot(int rin) {
    return (((rin >> 5) * 2 + ((rin >> 2) & 1)) << 4)
         + (((rin >> 3) & 3) << 2) + (rin & 3);
}

// ---------------------------------------------------------------------------
// 1. fused token2map scatter + all small prep work.
//    [0,16384)        scatter: segment-sum x_source -> feat, count -> maskr
//    [16384,20480)    wtrans srw -> wTb
//    [20480,20672)    cvt Wq/Wk/Wv -> wqb/wkb/wvb (wkb,wvb adjacent)
//    [20672,20928)    Wp split [bh|bl|bh] -> wpb
//    [20928,20936)    cf = conf*log2e as f32 into STG cf block [4864,4992) u16
//    [20936,25032)    x fp32 -> bf16 (xbf) for the Q-GEMM A operand
// ---------------------------------------------------------------------------
__global__ __launch_bounds__(256) void scatter_prep(
        const float* __restrict__ xsrc, const float* __restrict__ loc,
        float* __restrict__ feat, float* __restrict__ maskr,
        const float* __restrict__ srw, const float* __restrict__ Wq,
        const float* __restrict__ Wk, const float* __restrict__ Wv,
        const float* __restrict__ Wp, const float* __restrict__ conf,
        const float* __restrict__ x,
        unsigned short* __restrict__ wTb, unsigned short* __restrict__ wqb,
        unsigned short* __restrict__ wkb, unsigned short* __restrict__ wvb,
        unsigned short* __restrict__ wpb, unsigned short* __restrict__ stg,
        unsigned short* __restrict__ xbf) {
    int gid = blockIdx.x, tid = threadIdx.x;
    if (gid < 16384) {                      // scatter
        int token = gid;
        int b = token >> 13;
        float lx = loc[token * 2 + 0];
        float ly = loc[token * 2 + 1];
        lx = fminf(fmaxf(lx, 0.f), 1.f) * 127.0f;
        ly = fminf(fmaxf(ly, 0.f), 1.f) * 127.0f;
        int ix = __float2int_rn(lx);
        int iy = __float2int_rn(ly);
        int p = b * HWPIX + iy * WIDTH + ix;
        atomicAdd(&feat[(size_t)p * CD + tid], xsrc[(size_t)token * CD + tid]);
        if (tid == 0) atomicAdd(&maskr[p], 1.0f);
    } else if (gid < 20480) {               // sr_w transpose
        int idx = (gid - 16384) * 256 + tid;
        int co = idx >> 12;
        int rest = idx & 4095;
        int k16 = rest >> 8;
        int ci = rest & 255;
        int kh = k16 >> 2, kw = k16 & 3;
        wTb[idx] = f2bfu(srw[(size_t)co * 4096 + ci * 16 + kh * 4 + kw]);
    } else if (gid < 20672) {               // weight fp32 -> bf16
        const float* s; unsigned short* d; int base;
        if (gid < 20544)      { s = Wq; d = wqb; base = gid - 20480; }
        else if (gid < 20608) { s = Wk; d = wkb; base = gid - 20544; }
        else                  { s = Wv; d = wvb; base = gid - 20608; }
        int i = (base * 256 + tid) * 4;
        float4 v = *(const float4*)(s + i);
        ushort4 o;
        o.x = f2bfu(v.x); o.y = f2bfu(v.y); o.z = f2bfu(v.z); o.w = f2bfu(v.w);
        *(ushort4*)(d + i) = o;
    } else if (gid < 20928) {               // Wp split [bh|bl|bh]
        int n = gid - 20672, t = tid;
        float w = Wp[n * 256 + t];
        unsigned short hu = f2bfu(w);
        float hf = bits2f(((unsigned int)hu) << 16);
        unsigned short lu = f2bfu(w - hf);
        wpb[n * 768 + t]       = hu;
        wpb[n * 768 + 256 + t] = lu;
        wpb[n * 768 + 512 + t] = hu;
    } else if (gid < 20936) {               // cf floats into STG cf block
        int idx = (gid - 20928) * 256 + tid;  // b*1024 + key
        int b = idx >> 10, key = idx & 1023;
        int tile = key >> 6, rin = key & 63;
        int slot = kslot(rin);
        float val = conf[idx] * 1.4426950408889634f;
        #pragma unroll
        for (int h = 0; h < 8; h++)
            *(float*)&stg[((size_t)((b * 8 + h) * 16 + tile)) * 5120
                          + 4864 + slot * 2] = val;
    } else {                                // x fp32 -> bf16 (Q-GEMM A)
        size_t idx = ((size_t)(gid - 20936) * 256 + tid) * 4;
        float4 v = *(const float4*)(x + idx);
        ushort4 o;
        o.x = f2bfu(v.x); o.y = f2bfu(v.y); o.z = f2bfu(v.z); o.w = f2bfu(v.w);
        *(ushort4*)(xbf + idx) = o;
    }
}

// ---------------------------------------------------------------------------
// 2. recon body: fused normalize + 3x3 gaussian reconstruct + 4x4 patch
//    gather -> bf16 A. One block per 4x4 pixel patch. Shared arrays are
//    carved from the caller's LDS buffer (so recon can co-reside in the
//    same kernel as the Q-GEMM).
// ---------------------------------------------------------------------------
__device__ __forceinline__ void recon_body(unsigned short* SBraw,
        const float* __restrict__ feat, const float* __restrict__ maskr,
        unsigned short* __restrict__ apatch, int blk) {
    float* s_wci  = (float*)SBraw;        // [36] valid ? bin*inv : 0
    float* s_vb   = s_wci + 36;           // [36] valid ? bin : 0
    float* s_ginv = s_vb + 36;            // [16] gm>0 ? 1/(gm+1e-6) : 0
    float* s_omb  = s_ginv + 16;          // [16] 1 - bin(center)
    int*   s_np   = (int*)(s_omb + 16);   // [36] clamped pixel index
    int b  = blk >> 10;
    int py = (blk >> 5) & 31;
    int px = blk & 31;
    int c = threadIdx.x;
    const float e1 = 0.882496902584595f;
    const float e2 = 0.778800783071405f;
    const float snorm = 1.0f / (1.0f + 4.0f * e1 + 4.0f * e2);
    int y0 = py * 4 - 1, x0 = px * 4 - 1;
    if (c < 36) {
        int ry = c / 6, rx = c % 6;
        int yy = y0 + ry, xx = x0 + rx;
        bool valid = (yy >= 0 && yy <= 127 && xx >= 0 && xx <= 127);
        int yc = min(max(yy, 0), 127), xc = min(max(xx, 0), 127);
        int np_ = b * HWPIX + yc * WIDTH + xc;
        float m = maskr[np_];
        float bin = (m > 0.f) ? 1.f : 0.f;
        float inv = 1.0f / (m + 1e-6f);
        s_wci[c] = valid ? bin * inv : 0.f;
        s_vb[c]  = valid ? bin : 0.f;
        s_np[c]  = np_;
    }
    __syncthreads();
    if (c < 16) {                 // per-output-pixel channel-independent terms
        int oy = c >> 2, ox = c & 3;
        float gm = 0.f;
        #pragma unroll
        for (int dy = -1; dy <= 1; dy++)
            #pragma unroll
            for (int dx = -1; dx <= 1; dx++) {
                int manh = (dy != 0) + (dx != 0);
                float g = ((manh == 2) ? e2 : (manh == 1) ? e1 : 1.0f) * snorm;
                gm += g * s_vb[(oy + 1 + dy) * 6 + (ox + 1 + dx)];
            }
        s_ginv[c] = (gm > 0.f) ? 1.0f / (gm + 1e-6f) : 0.f;
        s_omb[c]  = 1.0f - s_vb[(oy + 1) * 6 + (ox + 1)];
    }
    float gf[4][4], fcv[4][4];
    #pragma unroll
    for (int oy = 0; oy < 4; oy++)
        #pragma unroll
        for (int ox = 0; ox < 4; ox++) { gf[oy][ox] = 0.f; fcv[oy][ox] = 0.f; }
    #pragma unroll
    for (int ry = 0; ry < 6; ry++) {
        #pragma unroll
        for (int rx = 0; rx < 6; rx++) {
            int j = ry * 6 + rx;
            float f = feat[(size_t)s_np[j] * CD + c] * s_wci[j];
            #pragma unroll
            for (int oy = 0; oy < 4; oy++) {
                int dy = ry - 1 - oy;
                if (dy < -1 || dy > 1) continue;
                #pragma unroll
                for (int ox = 0; ox < 4; ox++) {
                    int dx = rx - 1 - ox;
                    if (dx < -1 || dx > 1) continue;
                    int manh = (dy != 0) + (dx != 0);
                    float g = ((manh == 2) ? e2 : (manh == 1) ? e1 : 1.0f) * snorm;
                    gf[oy][ox] += g * f;
                }
            }
            if (ry >= 1 && ry <= 4 && rx >= 1 && rx <= 4)
                fcv[ry - 1][rx - 1] = f;   // = feat(center)*bin*inv
        }
    }
    __syncthreads();
    int r = b * 1024 + py * 32 + px;
    size_t base = (size_t)r * 4096 + c;
    #pragma unroll
    for (int oy = 0; oy < 4; oy++)
        #pragma unroll
        for (int ox = 0; ox < 4; ox++) {
            int i = oy * 4 + ox;
            float f_int = gf[oy][ox] * s_ginv[i];
            float res = fcv[oy][ox] + s_omb[i] * f_int;
            apatch[base + (size_t)i * 256] = f2bfu(res);
        }
}

// ---------------------------------------------------------------------------
// 3. bf16 MFMA GEMM v14: 64x128 tile, 4 waves, BK=32, async pipeline.
//    3 LDS buffers (12 KB each), global_load_lds staging, depth-2 prefetch
//    with counted s_waitcnt vmcnt(3) across one raw s_barrier per k-step.
//    Each wave issues exactly 3 loads per batch (1 A + 2 B chunks).
//    Ka = physical A row stride; kfold: logical k >= kfold maps to k-kfold.
//    mode 0: C fp32 = acc + bias[col]
//    mode 2: bf16 permuted write (Q)
//    mode 3: KV fused -> STG tiles (slot-perm K + V^T)
//    mode 4: split-K partials C[(bz*M + row)*N + col] = acc (no atomics)
// ---------------------------------------------------------------------------
__device__ __forceinline__ void bgemm64_body(
        unsigned short* SB,           // 3 * 6144 u16
        const unsigned short* __restrict__ A,
        const unsigned short* __restrict__ B, const float* __restrict__ bias,
        float* __restrict__ C, unsigned short* __restrict__ dstb,
        int M, int N, int K, int Ka, int kfold, int kSplit, int mode,
        float mult, int bx, int by, int bz) {
    int tid = threadIdx.x;
    int wave = tid >> 6, lane = tid & 63, m15 = lane & 15, quad = lane >> 4;
    int wr = (wave >> 1) * 32, wc = (wave & 1) * 64;
    int m0 = by * 64, n0 = bx * 128;
    int kchunk = K / kSplit, k0 = bz * kchunk;
    int nst = kchunk / 32;
    int srow = tid >> 2, sko = (tid & 3) * 8;
    f32x4 acc[2][4];
    #pragma unroll
    for (int i = 0; i < 2; i++)
        #pragma unroll
        for (int j = 0; j < 4; j++) acc[i][j] = (f32x4){0.f, 0.f, 0.f, 0.f};
    const unsigned short* Ag = A + (size_t)(m0 + srow) * Ka + sko;
    const unsigned short* Bg = B + (size_t)(n0 + srow) * K + k0 + sko;
    // prologue: stage batches 0,1 into buffers 0,1
    #pragma unroll
    for (int pt = 0; pt < 2; pt++) {
        int kl = k0 + pt * 32;
        int ke = (kfold && kl >= kfold) ? kl - kfold : kl;
        unsigned short* l = SB + pt * 6144;
        gld16(Ag + ke, l + wave * 512);
        gld16(Bg + pt * 32, l + 2048 + wave * 512);
        gld16(Bg + (size_t)64 * K + pt * 32, l + 4096 + wave * 512);
    }
    int cur = 0;
    for (int t = 0; t < nst; t++) {
        // counted wait: batch t complete; batch t+1 (3 loads) stays in flight
        if (t < nst - 1) asm volatile("s_waitcnt vmcnt(3)" ::: "memory");
        else             asm volatile("s_waitcnt vmcnt(0)" ::: "memory");
        __builtin_amdgcn_s_barrier();
        __builtin_amdgcn_sched_barrier(0);
        const unsigned short* SBc = SB + cur * 6144;
        bfrag af[2], bfr[4];
        #pragma unroll
        for (int mi = 0; mi < 2; mi++)
            af[mi] = *(const bfrag*)&SBc[(wr + mi * 16 + m15) * 32 + quad * 8];
        #pragma unroll
        for (int ni = 0; ni < 4; ni++)
            bfr[ni] = *(const bfrag*)&SBc[2048 + (wc + ni * 16 + m15) * 32
                                          + quad * 8];
        // issue async prefetch of batch t+2 into buffer (cur+2)%3
        if (t < nst - 2) {
            int nxt = cur + 2; if (nxt >= 3) nxt -= 3;
            int kl = k0 + (t + 2) * 32;
            int ke = (kfold && kl >= kfold) ? kl - kfold : kl;
            unsigned short* l = SB + nxt * 6144;
            gld16(Ag + ke, l + wave * 512);
            gld16(Bg + (t + 2) * 32, l + 2048 + wave * 512);
            gld16(Bg + (size_t)64 * K + (t + 2) * 32, l + 4096 + wave * 512);
        }
        __builtin_amdgcn_s_setprio(1);
        #pragma unroll
        for (int mi = 0; mi < 2; mi++)
            #pragma unroll
            for (int ni = 0; ni < 4; ni++)
                acc[mi][ni] = __builtin_amdgcn_mfma_f32_16x16x32_bf16(
                                  af[mi], bfr[ni], acc[mi][ni], 0, 0, 0);
        __builtin_amdgcn_s_setprio(0);
        cur = (cur == 2) ? 0 : cur + 1;
    }
    if (mode == 2) {
        #pragma unroll
        for (int mi = 0; mi < 2; mi++) {
            #pragma unroll
            for (int i = 0; i < 4; i++) {
                int row = m0 + wr + mi * 16 + quad * 4 + i;
                int b = row >> 13, r = row & 8191;
                #pragma unroll
                for (int ni = 0; ni < 4; ni++) {
                    int col = n0 + wc + ni * 16 + m15;
                    int h = col >> 5, d = col & 31;
                    size_t di = ((((size_t)(b * 8 + h)) << 13) + r) * 32 + d;
                    dstb[di] = f2bfu(acc[mi][ni][i] * mult);
                }
            }
        }
    } else if (mode == 3) {
        #pragma unroll
        for (int mi = 0; mi < 2; mi++) {
            #pragma unroll
            for (int i = 0; i < 4; i++) {
                int row = m0 + wr + mi * 16 + quad * 4 + i;
                int b = row >> 10, key = row & 1023;
                int tile = key >> 6, rin = key & 63;
                int slot = kslot(rin);
                #pragma unroll
                for (int ni = 0; ni < 4; ni++) {
                    int col = n0 + wc + ni * 16 + m15;
                    unsigned short v = f2bfu(acc[mi][ni][i]);
                    if (col < 256) {        // K part (slot-permuted rows)
                        int h = col >> 5, d = col & 31;
                        size_t di = ((size_t)((b * 8 + h) * 16 + tile)) * 5120
                                    + slot * 40 + d;
                        dstb[di] = v;
                    } else {                // V^T part (unpermuted keys)
                        int c2 = col - 256;
                        int h = c2 >> 5, d = c2 & 31;
                        size_t di = ((size_t)((b * 8 + h) * 16 + tile)) * 5120
                                    + 2560 + d * 72 + rin;
                        dstb[di] = v;
                    }
                }
            }
        }
    } else if (mode == 4) {
        #pragma unroll
        for (int mi = 0; mi < 2; mi++) {
            #pragma unroll
            for (int i = 0; i < 4; i++) {
                size_t row = ((size_t)bz * M + m0 + wr + mi * 16 + quad * 4 + i) * N;
                #pragma unroll
                for (int ni = 0; ni < 4; ni++) {
                    int col = n0 + wc + ni * 16 + m15;
                    C[row + col] = acc[mi][ni][i];
                }
            }
        }
    } else {
        #pragma unroll
        for (int mi = 0; mi < 2; mi++) {
            #pragma unroll
            for (int i = 0; i < 4; i++) {
                size_t row = (size_t)(m0 + wr + mi * 16 + quad * 4 + i) * N;
                #pragma unroll
                for (int ni = 0; ni < 4; ni++) {
                    int col = n0 + wc + ni * 16 + m15;
                    C[row + col] = acc[mi][ni][i] + (bias ? bias[col] : 0.f);
                }
            }
        }
    }
}

__global__ __launch_bounds__(256) void bgemm64(const unsigned short* A,
        const unsigned short* B, const float* bias,
        float* C, unsigned short* dstb,
        int M, int N, int K, int Ka, int kfold, int kSplit, int mode,
        float mult) {
    __shared__ __align__(16) unsigned short SB[3 * 6144];
    bgemm64_body(SB, A, B, bias, C, dstb, M, N, K, Ka, kfold, kSplit,
                 mode, mult, blockIdx.x, blockIdx.y, blockIdx.z);
}

// ---------------------------------------------------------------------------
// 2b. recon (2048 blocks) + Q-GEMM (512 blocks) co-scheduled in one launch:
//     recon is memory-bound (MFMA idle), Q-GEMM compute-bound (HBM light) —
//     complementary pipes. Q needs only xbf (ready after scatter_prep);
//     Qbf lives at a fresh arena slot so there is no overlap with feat.
// ---------------------------------------------------------------------------
__global__ __launch_bounds__(256) void recon_q(
        const float* __restrict__ feat, const float* __restrict__ maskr,
        unsigned short* __restrict__ apatch,
        const unsigned short* __restrict__ xbf,
        const unsigned short* __restrict__ wqb,
        unsigned short* __restrict__ Qbf, float SC) {
    __shared__ __align__(16) unsigned short SB[3 * 6144];
    int g = blockIdx.x;
    if (g < 2048) {
        recon_body(SB, feat, maskr, apatch, g);
    } else {
        int g2 = g - 2048;
        // Q = x@Wq^T * scale*log2e (A pre-cvt bf16) -> [bh][8192][32] bf16
        bgemm64_body(SB, xbf, wqb, nullptr, nullptr, Qbf,
                     16384, 256, 256, 256, 0, 1, 2, SC, g2 & 1, g2 >> 1, 0);
    }
}

// ---------------------------------------------------------------------------
// 4. fused split-K reduce (+conv bias) + LayerNorm (C=256), fp32 -> bf16
// ---------------------------------------------------------------------------
__global__ __launch_bounds__(256) void ln_red(const float* __restrict__ part,
        const float* __restrict__ srb, const float* __restrict__ w,
        const float* __restrict__ bvec, unsigned short* __restrict__ outb) {
    int row = blockIdx.x;
    int c = threadIdx.x;
    float v = srb[c];
    #pragma unroll
    for (int z = 0; z < 8; z++)
        v += part[((size_t)z * 2048 + row) * 256 + c];
    __shared__ float red[4];
    float s = v;
    #pragma unroll
    for (int o = 32; o >= 1; o >>= 1) s += __shfl_down(s, o, 64);
    if ((c & 63) == 0) red[c >> 6] = s;
    __syncthreads();
    float mean = (red[0] + red[1] + red[2] + red[3]) * (1.f / 256.f);
    __syncthreads();
    float d = v - mean;
    float s2 = d * d;
    #pragma unroll
    for (int o = 32; o >= 1; o >>= 1) s2 += __shfl_down(s2, o, 64);
    if ((c & 63) == 0) red[c >> 6] = s2;
    __syncthreads();
    float var = (red[0] + red[1] + red[2] + red[3]) * (1.f / 256.f);
    float r = 1.0f / sqrtf(var + 1e-5f);
    outb[(size_t)row * 256 + c] = f2bfu(d * r * w[c] + bvec[c]);
}

// ---------------------------------------------------------------------------
// 5. MFMA flash attention v13: 64 q-rows/wave, swapped QK^T, lane-local P,
//    l = P·1, depth-2 async pipeline (3 LDS buffers, counted vmcnt across
//    raw s_barrier), XCD-affinity swizzle, aout [16384][512] = [hi|lo].
//    Grid (32,16) = 512 blocks = 2 blocks/CU, __launch_bounds__(256,2).
// ---------------------------------------------------------------------------
__global__ __launch_bounds__(256, 2) void attn_v13(
        const unsigned short* __restrict__ Qb,   // [bh][8192][32] *scale*log2e
        const unsigned short* __restrict__ STG,  // [bh][16][5120 u16]
        unsigned short* __restrict__ aout) {     // [16384][512] hi|lo
    __shared__ __align__(16) unsigned short SB[3][5120];
    int tid  = threadIdx.x;
    int wave = tid >> 6;
    int lane = tid & 63;
    int m15  = lane & 15;
    int quad = lane >> 4;
    // XCD swizzle: flat%8 fixed per bh -> same XCD under round-robin dispatch
    int flat = blockIdx.y * 32 + blockIdx.x;
    int j  = flat >> 3;
    int bh = (flat & 7) + ((j >> 5) << 3);
    int b  = bh >> 3;
    int h  = bh & 7;
    int qbase = (j & 31) * 256 + wave * 64;

    // Q as the B-operand: lane holds Q[q=tq*16+m15][dh=quad*8+jj]
    const unsigned short* qp = Qb + ((size_t)bh * NTOK + qbase) * 32;
    bfrag Qa[4];
    #pragma unroll
    for (int tq = 0; tq < 4; tq++)
        Qa[tq] = *(const bfrag*)(qp + (tq * 16 + m15) * 32 + quad * 8);
    const unsigned short* sg = STG + (size_t)bh * 16 * 5120;

    bfrag ones;
    #pragma unroll
    for (int i = 0; i < 8; i++) ones[i] = (short)0x3F80;   // bf16 1.0

    f32x4 O[4][2];
    f32x4 Lac[4];
    #pragma unroll
    for (int tq = 0; tq < 4; tq++) {
        O[tq][0] = (f32x4){0.f, 0.f, 0.f, 0.f};
        O[tq][1] = (f32x4){0.f, 0.f, 0.f, 0.f};
        Lac[tq]  = (f32x4){0.f, 0.f, 0.f, 0.f};
    }

    // prologue: issue tiles 0,1 into SB[0],SB[1]
    // (10 chunks of 1 KB each; wave w: chunks w, w+4; waves 0,1 also 8,9)
    #pragma unroll
    for (int pt = 0; pt < 2; pt++) {
        const unsigned short* g = sg + (size_t)pt * 5120;
        unsigned short* l = &SB[pt][0];
        gld16(g + wave * 512 + lane * 8, l + wave * 512);
        gld16(g + (wave + 4) * 512 + lane * 8, l + (wave + 4) * 512);
        if (wave < 2) gld16(g + (8 + wave) * 512 + lane * 8, l + (8 + wave) * 512);
    }

    int cur = 0;
    for (int t = 0; t < 16; t++) {
        // counted wait: batch t done, batch t+1 stays in flight
        if (t < 15) {
            if (wave < 2) asm volatile("s_waitcnt vmcnt(3)" ::: "memory");
            else          asm volatile("s_waitcnt vmcnt(2)" ::: "memory");
        } else {
            asm volatile("s_waitcnt vmcnt(0)" ::: "memory");
        }
        __builtin_amdgcn_s_barrier();
        __builtin_amdgcn_sched_barrier(0);
        const unsigned short* Ks = &SB[0][0] + cur * 5120;
        const unsigned short* Vs = Ks + 2560;
        const float* Cf = (const float*)(Ks + 4864);
        // ---- K frags (A-operand rows = storage slots) + cf C-operand ----
        bfrag kf[4]; f32x4 ccf[4];
        #pragma unroll
        for (int s = 0; s < 4; s++) {
            kf[s]  = *(const bfrag*)&Ks[(s * 16 + m15) * 40 + quad * 8];
            ccf[s] = *(const f32x4*)&Cf[s * 16 + quad * 4];
        }
        // ---- issue async prefetch of tile t+2 into buf (cur+2)%3 ----
        if (t < 14) {
            int nxt = cur + 2; if (nxt >= 3) nxt -= 3;
            const unsigned short* g = sg + (size_t)(t + 2) * 5120;
            unsigned short* l = &SB[0][0] + nxt * 5120;
            gld16(g + wave * 512 + lane * 8, l + wave * 512);
            gld16(g + (wave + 4) * 512 + lane * 8, l + (wave + 4) * 512);
            if (wave < 2) gld16(g + (8 + wave) * 512 + lane * 8,
                                l + (8 + wave) * 512);
        }
        // ---- per tq: S^T = K Q^T + cf (4 MFMAs) -> exp2 -> lane-local
        //      pack into PV A-frags. Sequential tq keeps S/v transient. ----
        bfrag Pb[4][2];
        #pragma unroll
        for (int tq = 0; tq < 4; tq++) {
            f32x4 S[4];
            __builtin_amdgcn_s_setprio(1);
            #pragma unroll
            for (int s = 0; s < 4; s++)
                S[s] = __builtin_amdgcn_mfma_f32_16x16x32_bf16(kf[s], Qa[tq],
                                                               ccf[s], 0, 0, 0);
            __builtin_amdgcn_s_setprio(0);
            float v[4][4];
            #pragma unroll
            for (int s = 0; s < 4; s++)
                #pragma unroll
                for (int r = 0; r < 4; r++)
                    v[s][r] = __builtin_amdgcn_exp2f(S[s][r]);
            #pragma unroll
            for (int k2 = 0; k2 < 2; k2++) {
                u32x4 pw;
                pw[0] = cvtpk(v[2 * k2][0],     v[2 * k2][1]);
                pw[1] = cvtpk(v[2 * k2][2],     v[2 * k2][3]);
                pw[2] = cvtpk(v[2 * k2 + 1][0], v[2 * k2 + 1][1]);
                pw[3] = cvtpk(v[2 * k2 + 1][2], v[2 * k2 + 1][3]);
                Pb[tq][k2] = __builtin_bit_cast(bfrag, pw);
            }
        }
        // ---- V^T frags (late load: shorter liveness) ----
        bfrag vfr[2][2];
        #pragma unroll
        for (int k2 = 0; k2 < 2; k2++)
            #pragma unroll
            for (int dt = 0; dt < 2; dt++)
                vfr[k2][dt] = *(const bfrag*)&Vs[(dt * 16 + m15) * 72 +
                                                 k2 * 32 + quad * 8];
        // ---- O += P V ; l += P 1  (24 MFMAs, lane-aligned layouts) ----
        __builtin_amdgcn_s_setprio(1);
        #pragma unroll
        for (int k2 = 0; k2 < 2; k2++)
            #pragma unroll
            for (int tq = 0; tq < 4; tq++) {
                #pragma unroll
                for (int dt = 0; dt < 2; dt++)
                    O[tq][dt] = __builtin_amdgcn_mfma_f32_16x16x32_bf16(
                                    Pb[tq][k2], vfr[k2][dt], O[tq][dt], 0, 0, 0);
                Lac[tq] = __builtin_amdgcn_mfma_f32_16x16x32_bf16(
                                    Pb[tq][k2], ones, Lac[tq], 0, 0, 0);
            }
        __builtin_amdgcn_s_setprio(0);
        cur = (cur == 2) ? 0 : cur + 1;
    }
    // ---- epilogue: O/l -> split [hi|lo] bf16 into aout [16384][512] ----
    // Lac[tq][r] = l for q = tq*16+quad*4+r, identical across m15.
    #pragma unroll
    for (int tq = 0; tq < 4; tq++) {
        #pragma unroll
        for (int r = 0; r < 4; r++) {
            float inv = 1.0f / Lac[tq][r];
            int row = b * NTOK + qbase + tq * 16 + quad * 4 + r;
            size_t rb = (size_t)row * 512;
            #pragma unroll
            for (int dt = 0; dt < 2; dt++) {
                float o = O[tq][dt][r] * inv;
                unsigned int hr = rtn16(o);
                unsigned short hu = hr >> 16;
                float hf = bits2f(hr & 0xffff0000u);
                unsigned short lu = rtn16(o - hf) >> 16;
                int col = h * 32 + dt * 16 + m15;
                aout[rb + col]       = hu;
                aout[rb + 256 + col] = lu;
            }
        }
    }
}

// ---------------------------------------------------------------------------
extern "C" void kernel_launch(void* const* d_in, const int* in_sizes, int n_in,
                              void* d_out, int out_size, void* d_ws, size_t ws_size,
                              hipStream_t stream) {
    const float* x        = (const float*)d_in[0];
    const float* x_source = (const float*)d_in[1];
    const float* loc      = (const float*)d_in[2];
    const float* conf     = (const float*)d_in[3];
    const float* Wq       = (const float*)d_in[4];
    const float* Wk       = (const float*)d_in[5];
    const float* Wv       = (const float*)d_in[6];
    const float* srw      = (const float*)d_in[7];
    const float* srb      = (const float*)d_in[8];
    const float* lnw      = (const float*)d_in[9];
    const float* lnb      = (const float*)d_in[10];
    const float* Wp       = (const float*)d_in[11];
    const float* bp       = (const float*)d_in[12];
    float* out = (float*)d_out;
    float* ws  = (float*)d_ws;

    // ---- workspace arena (float offsets); ~99 MB total ----
    // A0 [0, 8388608): feat during scatter/recon (no overlay now).
    float* feat = ws;
    // A1 maskr
    float* maskr = ws + 8388608;                                //    32,768 f
    // A2 [8421376, 14712832): apatch (recon out) -> aouts (attn out,
    //    [16384][512] = 8,388,608 u16) overlay; wTb at the tail (dead after
    //    conv GEMM, before aouts written).
    unsigned short* apatch = (unsigned short*)(ws + 8421376);   // 8,388,608 u16
    unsigned short* aouts  = (unsigned short*)(ws + 8421376);   // 8,388,608 u16
    unsigned short* wTb    = (unsigned short*)(ws + 12615680);  // 1,048,576 u16
    // A3 [14712832, 16351232): scatter_prep outputs — NEVER overlaps feat.
    unsigned short* stg  = (unsigned short*)(ws + 14712832);    // 1,310,720 u16
    unsigned short* wqb  = (unsigned short*)(ws + 15368192);    //    65,536 u16
    unsigned short* wkb  = (unsigned short*)(ws + 15400960);    //  (B of KV:
    unsigned short* wvb  = (unsigned short*)(ws + 15433728);    //   adjacent)
    unsigned short* wpb  = (unsigned short*)(ws + 15466496);    //   196,608 u16
    unsigned short* xsbf = (unsigned short*)(ws + 16089088);    //   524,288 u16
    // A4 [16351232, ...): xbf (Q-GEMM A, bf16) + conv split-K partials
    unsigned short* xbf  = (unsigned short*)(ws + 16351232);    // 4,194,304 u16
    float*          part = ws + 18448384;                       // 4,194,304 f
    // A5: Qbf moved OUT of the feat overlay so Q-GEMM can run ∥ recon.
    unsigned short* Qbf  = (unsigned short*)(ws + 22642688);    // 4,194,304 u16

    const float SC = 0.17677669529663687f * 1.4426950408889634f; // scale*log2e

    // zero scatter accumulators (feat + maskr adjacent)
    hipMemsetAsync(feat, 0, (size_t)(8388608 + 32768) * sizeof(float), stream);

    scatter_prep<<<25032, 256, 0, stream>>>(x_source, loc, feat, maskr,
                                            srw, Wq, Wk, Wv, Wp, conf, x,
                                            wTb, wqb, wkb, wvb, wpb, stg, xbf);
    // recon (2048) + Q-GEMM (512) co-scheduled: complementary pipes
    recon_q<<<2560, 256, 0, stream>>>(feat, maskr, apatch, xbf, wqb, Qbf, SC);
    // conv as GEMM (2048 x 256 x 4096), split-K 8 -> partials (no atomics)
    bgemm64<<<dim3(2, 32, 8), 256, 0, stream>>>(apatch, wTb, nullptr,
                                                part, nullptr,
                                                2048, 256, 4096, 4096, 0,
                                                8, 4, 1.f);
    // fused split-K reduce + conv bias + LayerNorm
    ln_red<<<2048, 256, 0, stream>>>(part, srb, lnw, lnb, xsbf);
    // K|V fused GEMM (B=[Wk;Wv], N=512) -> STG tiles (slot-perm K + V^T)
    bgemm64<<<dim3(4, 32, 1), 256, 0, stream>>>(xsbf, wkb, nullptr,
                                                nullptr, stg,
                                                2048, 512, 256, 256, 0,
                                                1, 3, 1.f);
    attn_v13<<<dim3(32, 16), 256, 0, stream>>>(Qbf, stg, aouts);
    // final projection: logical K=768 (hi*wh + hi*wl + lo*wh) over the
    // 512-wide [hi|lo] A via kfold=256
    bgemm64<<<dim3(2, 256, 1), 256, 0, stream>>>(aouts, wpb, bp,
                                                 out, nullptr,
                                                 16384, 256, 768, 512, 256,
                                                 1, 0, 1.f);
}

// Round 10
// 210.756 us; speedup vs baseline: 1.0147x; 1.0147x over previous
//
#include <hip/hip_runtime.h>
#include <hip/hip_bf16.h>
#include <cstddef>
#include <cstdint>

#define NTOK 8192      // N
#define CD   256       // C
#define HWPIX 16384    // H*W = 128*128
#define WIDTH 128
#define NSEQ 1024      // Ns

typedef __attribute__((ext_vector_type(8))) short bfrag;   // 8 bf16 = 4 VGPRs
typedef __attribute__((ext_vector_type(4))) float f32x4;
typedef __attribute__((ext_vector_type(4))) unsigned int u32x4;

__device__ inline unsigned short f2bfu(float f) {
    __hip_bfloat16 h = __float2bfloat16(f);   // RTNE
    unsigned short u;
    __builtin_memcpy(&u, &h, 2);
    return u;
}
__device__ inline unsigned int rtn16(float f) {
    unsigned int u = __builtin_bit_cast(unsigned int, f);
    return u + 0x7fffu + ((u >> 16) & 1u);
}
__device__ inline float bits2f(unsigned int u) {
    return __builtin_bit_cast(float, u);
}
// async global -> LDS, 16 B per lane; lds base wave-uniform, HW adds lane*16
__device__ inline void gld16(const unsigned short* g, const unsigned short* l) {
    __builtin_amdgcn_global_load_lds(
        (const __attribute__((address_space(1))) unsigned int*)g,
        (__attribute__((address_space(3))) unsigned int*)l, 16, 0, 0);
}
// HW bf16 pack, RTNE: low16 = bf16(lo), high16 = bf16(hi). 1 instr.
__device__ inline unsigned int cvtpk(float lo, float hi) {
    unsigned int r;
    asm("v_cvt_pk_bf16_f32 %0, %1, %2" : "=v"(r) : "v"(lo), "v"(hi));
    return r;
}
// key (0..63 within tile) -> K storage slot. Bit permutation
// slot = [b5 b2 | b4 b3 | b1 b0] of key; chosen so that the swapped-QK
// MFMA D-layout (row = quad*4+reg, sub = s) leaves each lane holding
// exactly the keys of its own PV A-operand fragment (lane-local pack).
__device__ inline int kslot(int rin) {
    return (((rin >> 5) * 2 + ((rin >> 2) & 1)) << 4)
         + (((rin >> 3) & 3) << 2) + (rin & 3);
}

// ---------------------------------------------------------------------------
// 1. fused token2map scatter + all small prep work.
//    [0,16384)        scatter: segment-sum x_source -> feat, count -> maskr
//    [16384,20480)    wtrans srw -> wTb
//    [20480,20672)    cvt Wq/Wk/Wv -> wqb/wkb/wvb (wkb,wvb adjacent)
//    [20672,20928)    Wp split [bh|bl|bh] -> wpb
//    [20928,20936)    cf = conf*log2e as f32 into STG cf block [4864,4992) u16
//    [20936,25032)    x fp32 -> bf16 (xbf) for the Q-GEMM A operand
// ---------------------------------------------------------------------------
__global__ __launch_bounds__(256) void scatter_prep(
        const float* __restrict__ xsrc, const float* __restrict__ loc,
        float* __restrict__ feat, float* __restrict__ maskr,
        const float* __restrict__ srw, const float* __restrict__ Wq,
        const float* __restrict__ Wk, const float* __restrict__ Wv,
        const float* __restrict__ Wp, const float* __restrict__ conf,
        const float* __restrict__ x,
        unsigned short* __restrict__ wTb, unsigned short* __restrict__ wqb,
        unsigned short* __restrict__ wkb, unsigned short* __restrict__ wvb,
        unsigned short* __restrict__ wpb, unsigned short* __restrict__ stg,
        unsigned short* __restrict__ xbf) {
    int gid = blockIdx.x, tid = threadIdx.x;
    if (gid < 16384) {                      // scatter
        int token = gid;
        int b = token >> 13;
        float lx = loc[token * 2 + 0];
        float ly = loc[token * 2 + 1];
        lx = fminf(fmaxf(lx, 0.f), 1.f) * 127.0f;
        ly = fminf(fmaxf(ly, 0.f), 1.f) * 127.0f;
        int ix = __float2int_rn(lx);
        int iy = __float2int_rn(ly);
        int p = b * HWPIX + iy * WIDTH + ix;
        atomicAdd(&feat[(size_t)p * CD + tid], xsrc[(size_t)token * CD + tid]);
        if (tid == 0) atomicAdd(&maskr[p], 1.0f);
    } else if (gid < 20480) {               // sr_w transpose
        int idx = (gid - 16384) * 256 + tid;
        int co = idx >> 12;
        int rest = idx & 4095;
        int k16 = rest >> 8;
        int ci = rest & 255;
        int kh = k16 >> 2, kw = k16 & 3;
        wTb[idx] = f2bfu(srw[(size_t)co * 4096 + ci * 16 + kh * 4 + kw]);
    } else if (gid < 20672) {               // weight fp32 -> bf16
        const float* s; unsigned short* d; int base;
        if (gid < 20544)      { s = Wq; d = wqb; base = gid - 20480; }
        else if (gid < 20608) { s = Wk; d = wkb; base = gid - 20544; }
        else                  { s = Wv; d = wvb; base = gid - 20608; }
        int i = (base * 256 + tid) * 4;
        float4 v = *(const float4*)(s + i);
        ushort4 o;
        o.x = f2bfu(v.x); o.y = f2bfu(v.y); o.z = f2bfu(v.z); o.w = f2bfu(v.w);
        *(ushort4*)(d + i) = o;
    } else if (gid < 20928) {               // Wp split [bh|bl|bh]
        int n = gid - 20672, t = tid;
        float w = Wp[n * 256 + t];
        unsigned short hu = f2bfu(w);
        float hf = bits2f(((unsigned int)hu) << 16);
        unsigned short lu = f2bfu(w - hf);
        wpb[n * 768 + t]       = hu;
        wpb[n * 768 + 256 + t] = lu;
        wpb[n * 768 + 512 + t] = hu;
    } else if (gid < 20936) {               // cf floats into STG cf block
        int idx = (gid - 20928) * 256 + tid;  // b*1024 + key
        int b = idx >> 10, key = idx & 1023;
        int tile = key >> 6, rin = key & 63;
        int slot = kslot(rin);
        float val = conf[idx] * 1.4426950408889634f;
        #pragma unroll
        for (int h = 0; h < 8; h++)
            *(float*)&stg[((size_t)((b * 8 + h) * 16 + tile)) * 5120
                          + 4864 + slot * 2] = val;
    } else {                                // x fp32 -> bf16 (Q-GEMM A)
        size_t idx = ((size_t)(gid - 20936) * 256 + tid) * 4;
        float4 v = *(const float4*)(x + idx);
        ushort4 o;
        o.x = f2bfu(v.x); o.y = f2bfu(v.y); o.z = f2bfu(v.z); o.w = f2bfu(v.w);
        *(ushort4*)(xbf + idx) = o;
    }
}

// ---------------------------------------------------------------------------
// 2. fused normalize + 3x3 gaussian reconstruct + 4x4 patch gather -> bf16 A
//    Patch-blocked: one block per 4x4 pixel patch (grid 2048). Reads the
//    6x6 neighborhood once (36 KB / 16 pixels) instead of 10 KB/pixel.
//    NOTE (R8 post-mortem): keeping this a SEPARATE small-LDS kernel matters
//    — merging with the Q-GEMM (R8's recon_q) regressed 2.8 µs because the
//    unified kernel's regalloc/LDS dropped recon's occupancy.
// ---------------------------------------------------------------------------
__global__ __launch_bounds__(256) void recon_patch(const float* __restrict__ feat,
        const float* __restrict__ maskr, unsigned short* __restrict__ apatch) {
    __shared__ float s_wci[36];   // valid ? bin*inv : 0
    __shared__ float s_vb[36];    // valid ? bin : 0
    __shared__ int   s_np[36];    // clamped pixel index (safe load)
    __shared__ float s_ginv[16];  // gm>0 ? 1/(gm+1e-6) : 0
    __shared__ float s_omb[16];   // 1 - bin(center)
    int blk = blockIdx.x;
    int b  = blk >> 10;
    int py = (blk >> 5) & 31;
    int px = blk & 31;
    int c = threadIdx.x;
    const float e1 = 0.882496902584595f;
    const float e2 = 0.778800783071405f;
    const float snorm = 1.0f / (1.0f + 4.0f * e1 + 4.0f * e2);
    int y0 = py * 4 - 1, x0 = px * 4 - 1;
    if (c < 36) {
        int ry = c / 6, rx = c % 6;
        int yy = y0 + ry, xx = x0 + rx;
        bool valid = (yy >= 0 && yy <= 127 && xx >= 0 && xx <= 127);
        int yc = min(max(yy, 0), 127), xc = min(max(xx, 0), 127);
        int np_ = b * HWPIX + yc * WIDTH + xc;
        float m = maskr[np_];
        float bin = (m > 0.f) ? 1.f : 0.f;
        float inv = 1.0f / (m + 1e-6f);
        s_wci[c] = valid ? bin * inv : 0.f;
        s_vb[c]  = valid ? bin : 0.f;
        s_np[c]  = np_;
    }
    __syncthreads();
    if (c < 16) {                 // per-output-pixel channel-independent terms
        int oy = c >> 2, ox = c & 3;
        float gm = 0.f;
        #pragma unroll
        for (int dy = -1; dy <= 1; dy++)
            #pragma unroll
            for (int dx = -1; dx <= 1; dx++) {
                int manh = (dy != 0) + (dx != 0);
                float g = ((manh == 2) ? e2 : (manh == 1) ? e1 : 1.0f) * snorm;
                gm += g * s_vb[(oy + 1 + dy) * 6 + (ox + 1 + dx)];
            }
        s_ginv[c] = (gm > 0.f) ? 1.0f / (gm + 1e-6f) : 0.f;
        s_omb[c]  = 1.0f - s_vb[(oy + 1) * 6 + (ox + 1)];
    }
    float gf[4][4], fcv[4][4];
    #pragma unroll
    for (int oy = 0; oy < 4; oy++)
        #pragma unroll
        for (int ox = 0; ox < 4; ox++) { gf[oy][ox] = 0.f; fcv[oy][ox] = 0.f; }
    #pragma unroll
    for (int ry = 0; ry < 6; ry++) {
        #pragma unroll
        for (int rx = 0; rx < 6; rx++) {
            int j = ry * 6 + rx;
            float f = feat[(size_t)s_np[j] * CD + c] * s_wci[j];
            #pragma unroll
            for (int oy = 0; oy < 4; oy++) {
                int dy = ry - 1 - oy;
                if (dy < -1 || dy > 1) continue;
                #pragma unroll
                for (int ox = 0; ox < 4; ox++) {
                    int dx = rx - 1 - ox;
                    if (dx < -1 || dx > 1) continue;
                    int manh = (dy != 0) + (dx != 0);
                    float g = ((manh == 2) ? e2 : (manh == 1) ? e1 : 1.0f) * snorm;
                    gf[oy][ox] += g * f;
                }
            }
            if (ry >= 1 && ry <= 4 && rx >= 1 && rx <= 4)
                fcv[ry - 1][rx - 1] = f;   // = feat(center)*bin*inv
        }
    }
    __syncthreads();
    int r = b * 1024 + py * 32 + px;
    size_t base = (size_t)r * 4096 + c;
    #pragma unroll
    for (int oy = 0; oy < 4; oy++)
        #pragma unroll
        for (int ox = 0; ox < 4; ox++) {
            int i = oy * 4 + ox;
            float f_int = gf[oy][ox] * s_ginv[i];
            float res = fcv[oy][ox] + s_omb[i] * f_int;
            apatch[base + (size_t)i * 256] = f2bfu(res);
        }
}

// ---------------------------------------------------------------------------
// 3. bf16 MFMA GEMM v14: 64x128 tile, 4 waves, BK=32, async pipeline.
//    3 LDS buffers (12 KB each: As 4 KB + Bs 8 KB), global_load_lds staging
//    (the block's lane->LDS map is exactly tid*16 B = the HW linear pattern),
//    depth-2 prefetch with counted s_waitcnt vmcnt(3) across one raw
//    s_barrier per k-step (ledger identical to attn_v13: buffer written at
//    t+2 was last read at t-1, separated by the top-of-t barrier). Each wave
//    issues exactly 3 loads per batch (1 A + 2 B chunks) -> uniform count.
//    Ka = physical A row stride; kfold: logical k >= kfold maps to k-kfold.
//    mode 0: C fp32 = acc + bias[col]
//    mode 2: bf16 permuted write (Q)
//    mode 3: KV fused -> STG tiles (slot-perm K + V^T)
//    mode 4: split-K partials C[(bz*M + row)*N + col] = acc (no atomics)
// ---------------------------------------------------------------------------
__device__ __forceinline__ void bgemm64_body(
        unsigned short* SB,           // 3 * 6144 u16
        const unsigned short* __restrict__ A,
        const unsigned short* __restrict__ B, const float* __restrict__ bias,
        float* __restrict__ C, unsigned short* __restrict__ dstb,
        int M, int N, int K, int Ka, int kfold, int kSplit, int mode,
        float mult, int bx, int by, int bz) {
    int tid = threadIdx.x;
    int wave = tid >> 6, lane = tid & 63, m15 = lane & 15, quad = lane >> 4;
    int wr = (wave >> 1) * 32, wc = (wave & 1) * 64;
    int m0 = by * 64, n0 = bx * 128;
    int kchunk = K / kSplit, k0 = bz * kchunk;
    int nst = kchunk / 32;
    int srow = tid >> 2, sko = (tid & 3) * 8;
    f32x4 acc[2][4];
    #pragma unroll
    for (int i = 0; i < 2; i++)
        #pragma unroll
        for (int j = 0; j < 4; j++) acc[i][j] = (f32x4){0.f, 0.f, 0.f, 0.f};
    const unsigned short* Ag = A + (size_t)(m0 + srow) * Ka + sko;
    const unsigned short* Bg = B + (size_t)(n0 + srow) * K + k0 + sko;
    // prologue: stage batches 0,1 into buffers 0,1
    #pragma unroll
    for (int pt = 0; pt < 2; pt++) {
        int kl = k0 + pt * 32;
        int ke = (kfold && kl >= kfold) ? kl - kfold : kl;
        unsigned short* l = SB + pt * 6144;
        gld16(Ag + ke, l + wave * 512);
        gld16(Bg + pt * 32, l + 2048 + wave * 512);
        gld16(Bg + (size_t)64 * K + pt * 32, l + 4096 + wave * 512);
    }
    int cur = 0;
    for (int t = 0; t < nst; t++) {
        // counted wait: batch t complete; batch t+1 (3 loads) stays in flight
        if (t < nst - 1) asm volatile("s_waitcnt vmcnt(3)" ::: "memory");
        else             asm volatile("s_waitcnt vmcnt(0)" ::: "memory");
        __builtin_amdgcn_s_barrier();
        __builtin_amdgcn_sched_barrier(0);
        const unsigned short* SBc = SB + cur * 6144;
        bfrag af[2], bfr[4];
        #pragma unroll
        for (int mi = 0; mi < 2; mi++)
            af[mi] = *(const bfrag*)&SBc[(wr + mi * 16 + m15) * 32 + quad * 8];
        #pragma unroll
        for (int ni = 0; ni < 4; ni++)
            bfr[ni] = *(const bfrag*)&SBc[2048 + (wc + ni * 16 + m15) * 32
                                          + quad * 8];
        // issue async prefetch of batch t+2 into buffer (cur+2)%3
        if (t < nst - 2) {
            int nxt = cur + 2; if (nxt >= 3) nxt -= 3;
            int kl = k0 + (t + 2) * 32;
            int ke = (kfold && kl >= kfold) ? kl - kfold : kl;
            unsigned short* l = SB + nxt * 6144;
            gld16(Ag + ke, l + wave * 512);
            gld16(Bg + (t + 2) * 32, l + 2048 + wave * 512);
            gld16(Bg + (size_t)64 * K + (t + 2) * 32, l + 4096 + wave * 512);
        }
        __builtin_amdgcn_s_setprio(1);
        #pragma unroll
        for (int mi = 0; mi < 2; mi++)
            #pragma unroll
            for (int ni = 0; ni < 4; ni++)
                acc[mi][ni] = __builtin_amdgcn_mfma_f32_16x16x32_bf16(
                                  af[mi], bfr[ni], acc[mi][ni], 0, 0, 0);
        __builtin_amdgcn_s_setprio(0);
        cur = (cur == 2) ? 0 : cur + 1;
    }
    if (mode == 2) {
        #pragma unroll
        for (int mi = 0; mi < 2; mi++) {
            #pragma unroll
            for (int i = 0; i < 4; i++) {
                int row = m0 + wr + mi * 16 + quad * 4 + i;
                int b = row >> 13, r = row & 8191;
                #pragma unroll
                for (int ni = 0; ni < 4; ni++) {
                    int col = n0 + wc + ni * 16 + m15;
                    int h = col >> 5, d = col & 31;
                    size_t di = ((((size_t)(b * 8 + h)) << 13) + r) * 32 + d;
                    dstb[di] = f2bfu(acc[mi][ni][i] * mult);
                }
            }
        }
    } else if (mode == 3) {
        #pragma unroll
        for (int mi = 0; mi < 2; mi++) {
            #pragma unroll
            for (int i = 0; i < 4; i++) {
                int row = m0 + wr + mi * 16 + quad * 4 + i;
                int b = row >> 10, key = row & 1023;
                int tile = key >> 6, rin = key & 63;
                int slot = kslot(rin);
                #pragma unroll
                for (int ni = 0; ni < 4; ni++) {
                    int col = n0 + wc + ni * 16 + m15;
                    unsigned short v = f2bfu(acc[mi][ni][i]);
                    if (col < 256) {        // K part (slot-permuted rows)
                        int h = col >> 5, d = col & 31;
                        size_t di = ((size_t)((b * 8 + h) * 16 + tile)) * 5120
                                    + slot * 40 + d;
                        dstb[di] = v;
                    } else {                // V^T part (unpermuted keys)
                        int c2 = col - 256;
                        int h = c2 >> 5, d = c2 & 31;
                        size_t di = ((size_t)((b * 8 + h) * 16 + tile)) * 5120
                                    + 2560 + d * 72 + rin;
                        dstb[di] = v;
                    }
                }
            }
        }
    } else if (mode == 4) {
        #pragma unroll
        for (int mi = 0; mi < 2; mi++) {
            #pragma unroll
            for (int i = 0; i < 4; i++) {
                size_t row = ((size_t)bz * M + m0 + wr + mi * 16 + quad * 4 + i) * N;
                #pragma unroll
                for (int ni = 0; ni < 4; ni++) {
                    int col = n0 + wc + ni * 16 + m15;
                    C[row + col] = acc[mi][ni][i];
                }
            }
        }
    } else {
        #pragma unroll
        for (int mi = 0; mi < 2; mi++) {
            #pragma unroll
            for (int i = 0; i < 4; i++) {
                size_t row = (size_t)(m0 + wr + mi * 16 + quad * 4 + i) * N;
                #pragma unroll
                for (int ni = 0; ni < 4; ni++) {
                    int col = n0 + wc + ni * 16 + m15;
                    C[row + col] = acc[mi][ni][i] + (bias ? bias[col] : 0.f);
                }
            }
        }
    }
}

__global__ __launch_bounds__(256) void bgemm64(const unsigned short* A,
        const unsigned short* B, const float* bias,
        float* C, unsigned short* dstb,
        int M, int N, int K, int Ka, int kfold, int kSplit, int mode,
        float mult) {
    __shared__ __align__(16) unsigned short SB[3 * 6144];
    bgemm64_body(SB, A, B, bias, C, dstb, M, N, K, Ka, kfold, kSplit,
                 mode, mult, blockIdx.x, blockIdx.y, blockIdx.z);
}

// Q-GEMM (512 blocks) and KV-GEMM (128 blocks) co-scheduled in one launch
__global__ __launch_bounds__(256) void qkv_fused(const unsigned short* xbf,
        const unsigned short* wqb, const unsigned short* xsbf,
        const unsigned short* wkb, unsigned short* Qbf,
        unsigned short* stg, float SC) {
    __shared__ __align__(16) unsigned short SB[3 * 6144];
    int g = blockIdx.x;
    if (g < 512) {
        // Q = x@Wq^T * scale*log2e (A pre-cvt bf16) -> [bh][8192][32] bf16
        bgemm64_body(SB, xbf, wqb, nullptr, nullptr, Qbf,
                     16384, 256, 256, 256, 0, 1, 2, SC, g & 1, g >> 1, 0);
    } else {
        // K|V fused (B=[Wk;Wv], N=512) -> STG tiles (slot-perm K + V^T)
        int g2 = g - 512;
        bgemm64_body(SB, xsbf, wkb, nullptr, nullptr, stg,
                     2048, 512, 256, 256, 0, 1, 3, 1.f, g2 & 3, g2 >> 2, 0);
    }
}

// ---------------------------------------------------------------------------
// 4. fused split-K reduce (+conv bias) + LayerNorm (C=256), fp32 -> bf16
// ---------------------------------------------------------------------------
__global__ __launch_bounds__(256) void ln_red(const float* __restrict__ part,
        const float* __restrict__ srb, const float* __restrict__ w,
        const float* __restrict__ bvec, unsigned short* __restrict__ outb) {
    int row = blockIdx.x;
    int c = threadIdx.x;
    float v = srb[c];
    #pragma unroll
    for (int z = 0; z < 8; z++)
        v += part[((size_t)z * 2048 + row) * 256 + c];
    __shared__ float red[4];
    float s = v;
    #pragma unroll
    for (int o = 32; o >= 1; o >>= 1) s += __shfl_down(s, o, 64);
    if ((c & 63) == 0) red[c >> 6] = s;
    __syncthreads();
    float mean = (red[0] + red[1] + red[2] + red[3]) * (1.f / 256.f);
    __syncthreads();
    float d = v - mean;
    float s2 = d * d;
    #pragma unroll
    for (int o = 32; o >= 1; o >>= 1) s2 += __shfl_down(s2, o, 64);
    if ((c & 63) == 0) red[c >> 6] = s2;
    __syncthreads();
    float var = (red[0] + red[1] + red[2] + red[3]) * (1.f / 256.f);
    float r = 1.0f / sqrtf(var + 1e-5f);
    outb[(size_t)row * 256 + c] = f2bfu(d * r * w[c] + bvec[c]);
}

// ---------------------------------------------------------------------------
// 5. MFMA flash attention v13: 64 q-rows/wave, swapped QK^T, lane-local P,
//    l = P·1, depth-2 async pipeline (3 LDS buffers, counted vmcnt across
//    raw s_barrier), XCD-affinity swizzle, aout [16384][512] = [hi|lo].
//    Grid (32,16) = 512 blocks = 2 blocks/CU, __launch_bounds__(256,2).
// ---------------------------------------------------------------------------
__global__ __launch_bounds__(256, 2) void attn_v13(
        const unsigned short* __restrict__ Qb,   // [bh][8192][32] *scale*log2e
        const unsigned short* __restrict__ STG,  // [bh][16][5120 u16]
        unsigned short* __restrict__ aout) {     // [16384][512] hi|lo
    __shared__ __align__(16) unsigned short SB[3][5120];
    int tid  = threadIdx.x;
    int wave = tid >> 6;
    int lane = tid & 63;
    int m15  = lane & 15;
    int quad = lane >> 4;
    // XCD swizzle: flat%8 fixed per bh -> same XCD under round-robin dispatch
    int flat = blockIdx.y * 32 + blockIdx.x;
    int j  = flat >> 3;
    int bh = (flat & 7) + ((j >> 5) << 3);
    int b  = bh >> 3;
    int h  = bh & 7;
    int qbase = (j & 31) * 256 + wave * 64;

    // Q as the B-operand: lane holds Q[q=tq*16+m15][dh=quad*8+jj]
    const unsigned short* qp = Qb + ((size_t)bh * NTOK + qbase) * 32;
    bfrag Qa[4];
    #pragma unroll
    for (int tq = 0; tq < 4; tq++)
        Qa[tq] = *(const bfrag*)(qp + (tq * 16 + m15) * 32 + quad * 8);
    const unsigned short* sg = STG + (size_t)bh * 16 * 5120;

    bfrag ones;
    #pragma unroll
    for (int i = 0; i < 8; i++) ones[i] = (short)0x3F80;   // bf16 1.0

    f32x4 O[4][2];
    f32x4 Lac[4];
    #pragma unroll
    for (int tq = 0; tq < 4; tq++) {
        O[tq][0] = (f32x4){0.f, 0.f, 0.f, 0.f};
        O[tq][1] = (f32x4){0.f, 0.f, 0.f, 0.f};
        Lac[tq]  = (f32x4){0.f, 0.f, 0.f, 0.f};
    }

    // prologue: issue tiles 0,1 into SB[0],SB[1]
    // (10 chunks of 1 KB each; wave w: chunks w, w+4; waves 0,1 also 8,9)
    #pragma unroll
    for (int pt = 0; pt < 2; pt++) {
        const unsigned short* g = sg + (size_t)pt * 5120;
        unsigned short* l = &SB[pt][0];
        gld16(g + wave * 512 + lane * 8, l + wave * 512);
        gld16(g + (wave + 4) * 512 + lane * 8, l + (wave + 4) * 512);
        if (wave < 2) gld16(g + (8 + wave) * 512 + lane * 8, l + (8 + wave) * 512);
    }

    int cur = 0;
    for (int t = 0; t < 16; t++) {
        // counted wait: batch t done, batch t+1 stays in flight
        if (t < 15) {
            if (wave < 2) asm volatile("s_waitcnt vmcnt(3)" ::: "memory");
            else          asm volatile("s_waitcnt vmcnt(2)" ::: "memory");
        } else {
            asm volatile("s_waitcnt vmcnt(0)" ::: "memory");
        }
        __builtin_amdgcn_s_barrier();
        __builtin_amdgcn_sched_barrier(0);
        const unsigned short* Ks = &SB[0][0] + cur * 5120;
        const unsigned short* Vs = Ks + 2560;
        const float* Cf = (const float*)(Ks + 4864);
        // ---- K frags (A-operand rows = storage slots) + cf C-operand ----
        bfrag kf[4]; f32x4 ccf[4];
        #pragma unroll
        for (int s = 0; s < 4; s++) {
            kf[s]  = *(const bfrag*)&Ks[(s * 16 + m15) * 40 + quad * 8];
            ccf[s] = *(const f32x4*)&Cf[s * 16 + quad * 4];
        }
        // ---- issue async prefetch of tile t+2 into buf (cur+2)%3 ----
        if (t < 14) {
            int nxt = cur + 2; if (nxt >= 3) nxt -= 3;
            const unsigned short* g = sg + (size_t)(t + 2) * 5120;
            unsigned short* l = &SB[0][0] + nxt * 5120;
            gld16(g + wave * 512 + lane * 8, l + wave * 512);
            gld16(g + (wave + 4) * 512 + lane * 8, l + (wave + 4) * 512);
            if (wave < 2) gld16(g + (8 + wave) * 512 + lane * 8,
                                l + (8 + wave) * 512);
        }
        // ---- per tq: S^T = K Q^T + cf (4 MFMAs) -> exp2 -> lane-local
        //      pack into PV A-frags. Sequential tq keeps S/v transient. ----
        bfrag Pb[4][2];
        #pragma unroll
        for (int tq = 0; tq < 4; tq++) {
            f32x4 S[4];
            __builtin_amdgcn_s_setprio(1);
            #pragma unroll
            for (int s = 0; s < 4; s++)
                S[s] = __builtin_amdgcn_mfma_f32_16x16x32_bf16(kf[s], Qa[tq],
                                                               ccf[s], 0, 0, 0);
            __builtin_amdgcn_s_setprio(0);
            float v[4][4];
            #pragma unroll
            for (int s = 0; s < 4; s++)
                #pragma unroll
                for (int r = 0; r < 4; r++)
                    v[s][r] = __builtin_amdgcn_exp2f(S[s][r]);
            #pragma unroll
            for (int k2 = 0; k2 < 2; k2++) {
                u32x4 pw;
                pw[0] = cvtpk(v[2 * k2][0],     v[2 * k2][1]);
                pw[1] = cvtpk(v[2 * k2][2],     v[2 * k2][3]);
                pw[2] = cvtpk(v[2 * k2 + 1][0], v[2 * k2 + 1][1]);
                pw[3] = cvtpk(v[2 * k2 + 1][2], v[2 * k2 + 1][3]);
                Pb[tq][k2] = __builtin_bit_cast(bfrag, pw);
            }
        }
        // ---- V^T frags (late load: shorter liveness) ----
        bfrag vfr[2][2];
        #pragma unroll
        for (int k2 = 0; k2 < 2; k2++)
            #pragma unroll
            for (int dt = 0; dt < 2; dt++)
                vfr[k2][dt] = *(const bfrag*)&Vs[(dt * 16 + m15) * 72 +
                                                 k2 * 32 + quad * 8];
        // ---- O += P V ; l += P 1  (24 MFMAs, lane-aligned layouts) ----
        __builtin_amdgcn_s_setprio(1);
        #pragma unroll
        for (int k2 = 0; k2 < 2; k2++)
            #pragma unroll
            for (int tq = 0; tq < 4; tq++) {
                #pragma unroll
                for (int dt = 0; dt < 2; dt++)
                    O[tq][dt] = __builtin_amdgcn_mfma_f32_16x16x32_bf16(
                                    Pb[tq][k2], vfr[k2][dt], O[tq][dt], 0, 0, 0);
                Lac[tq] = __builtin_amdgcn_mfma_f32_16x16x32_bf16(
                                    Pb[tq][k2], ones, Lac[tq], 0, 0, 0);
            }
        __builtin_amdgcn_s_setprio(0);
        cur = (cur == 2) ? 0 : cur + 1;
    }
    // ---- epilogue: O/l -> split [hi|lo] bf16 into aout [16384][512] ----
    // Lac[tq][r] = l for q = tq*16+quad*4+r, identical across m15.
    #pragma unroll
    for (int tq = 0; tq < 4; tq++) {
        #pragma unroll
        for (int r = 0; r < 4; r++) {
            float inv = 1.0f / Lac[tq][r];
            int row = b * NTOK + qbase + tq * 16 + quad * 4 + r;
            size_t rb = (size_t)row * 512;
            #pragma unroll
            for (int dt = 0; dt < 2; dt++) {
                float o = O[tq][dt][r] * inv;
                unsigned int hr = rtn16(o);
                unsigned short hu = hr >> 16;
                float hf = bits2f(hr & 0xffff0000u);
                unsigned short lu = rtn16(o - hf) >> 16;
                int col = h * 32 + dt * 16 + m15;
                aout[rb + col]       = hu;
                aout[rb + 256 + col] = lu;
            }
        }
    }
}

// ---------------------------------------------------------------------------
extern "C" void kernel_launch(void* const* d_in, const int* in_sizes, int n_in,
                              void* d_out, int out_size, void* d_ws, size_t ws_size,
                              hipStream_t stream) {
    const float* x        = (const float*)d_in[0];
    const float* x_source = (const float*)d_in[1];
    const float* loc      = (const float*)d_in[2];
    const float* conf     = (const float*)d_in[3];
    const float* Wq       = (const float*)d_in[4];
    const float* Wk       = (const float*)d_in[5];
    const float* Wv       = (const float*)d_in[6];
    const float* srw      = (const float*)d_in[7];
    const float* srb      = (const float*)d_in[8];
    const float* lnw      = (const float*)d_in[9];
    const float* lnb      = (const float*)d_in[10];
    const float* Wp       = (const float*)d_in[11];
    const float* bp       = (const float*)d_in[12];
    float* out = (float*)d_out;
    float* ws  = (float*)d_ws;

    // ---- workspace arena (float offsets); ~91 MB total ----
    // A0 [0, 8388608): feat during scatter/recon; Qbf overlaid after recon.
    float* feat = ws;
    unsigned short* Qbf = (unsigned short*)ws;                  // 4,194,304 u16
    // A1 maskr
    float* maskr = ws + 8388608;                                //    32,768 f
    // A2 [8421376, 14712832): apatch (recon out) -> aouts (attn out,
    //    [16384][512] = 8,388,608 u16) overlay; wTb at the tail (dead after
    //    conv GEMM, before aouts written).
    unsigned short* apatch = (unsigned short*)(ws + 8421376);   // 8,388,608 u16
    unsigned short* aouts  = (unsigned short*)(ws + 8421376);   // 8,388,608 u16
    unsigned short* wTb    = (unsigned short*)(ws + 12615680);  // 1,048,576 u16
    // A3 [14712832, 16351232): scatter_prep outputs — NEVER overlaps feat.
    unsigned short* stg  = (unsigned short*)(ws + 14712832);    // 1,310,720 u16
    unsigned short* wqb  = (unsigned short*)(ws + 15368192);    //    65,536 u16
    unsigned short* wkb  = (unsigned short*)(ws + 15400960);    //  (B of KV:
    unsigned short* wvb  = (unsigned short*)(ws + 15433728);    //   adjacent)
    unsigned short* wpb  = (unsigned short*)(ws + 15466496);    //   196,608 u16
    unsigned short* xsbf = (unsigned short*)(ws + 16089088);    //   524,288 u16
    // A4 [16351232, ...): xbf (Q-GEMM A, bf16) + conv split-K partials
    unsigned short* xbf  = (unsigned short*)(ws + 16351232);    // 4,194,304 u16
    float*          part = ws + 18448384;                       // 4,194,304 f

    const float SC = 0.17677669529663687f * 1.4426950408889634f; // scale*log2e

    // zero scatter accumulators (feat + maskr adjacent)
    hipMemsetAsync(feat, 0, (size_t)(8388608 + 32768) * sizeof(float), stream);

    scatter_prep<<<25032, 256, 0, stream>>>(x_source, loc, feat, maskr,
                                            srw, Wq, Wk, Wv, Wp, conf, x,
                                            wTb, wqb, wkb, wvb, wpb, stg, xbf);
    recon_patch<<<2048, 256, 0, stream>>>(feat, maskr, apatch);
    // conv as GEMM (2048 x 256 x 4096), split-K 8 -> partials (no atomics)
    bgemm64<<<dim3(2, 32, 8), 256, 0, stream>>>(apatch, wTb, nullptr,
                                                part, nullptr,
                                                2048, 256, 4096, 4096, 0,
                                                8, 4, 1.f);
    // fused split-K reduce + conv bias + LayerNorm
    ln_red<<<2048, 256, 0, stream>>>(part, srb, lnw, lnb, xsbf);
    // Q-GEMM (512 blocks) + KV-GEMM (128 blocks) in one launch
    qkv_fused<<<640, 256, 0, stream>>>(xbf, wqb, xsbf, wkb, Qbf, stg, SC);
    attn_v13<<<dim3(32, 16), 256, 0, stream>>>(Qbf, stg, aouts);
    // final projection: logical K=768 (hi*wh + hi*wl + lo*wh) over the
    // 512-wide [hi|lo] A via kfold=256
    bgemm64<<<dim3(2, 256, 1), 256, 0, stream>>>(aouts, wpb, bp,
                                                 out, nullptr,
                                                 16384, 256, 768, 512, 256,
                                                 1, 0, 1.f);
}